// Round 1
// baseline (71.793 us; speedup 1.0000x reference)
//
#include <hip/hip_runtime.h>
#include <math.h>

#define N_GAUSS 2048
#define IMG_H 512
#define IMG_W 512

__global__ void zero_kernel(float4* __restrict__ out, int n4) {
    int i = blockIdx.x * blockDim.x + threadIdx.x;
    if (i < n4) out[i] = make_float4(0.f, 0.f, 0.f, 0.f);
}

__global__ __launch_bounds__(64) void splat_kernel(
    const float* __restrict__ xyz,
    const float* __restrict__ chol,
    const float* __restrict__ opacity,
    const float* __restrict__ fdc,
    float* __restrict__ out)
{
    const int g = blockIdx.x;        // one gaussian per 64-lane wave
    const int lane = threadIdx.x;

    // --- per-gaussian params, computed redundantly by all lanes (cheap) ---
    float mx = tanhf(xyz[2 * g]);
    float my = tanhf(xyz[2 * g + 1]);
    float l1 = chol[3 * g]     + 0.5f;   // cholesky_bound = [0.5, 0, 0.5]
    float l2 = chol[3 * g + 1];
    float l3 = chol[3 * g + 2] + 0.5f;

    float s11 = l1 * l1;
    float s12 = l1 * l2;
    float s22 = l2 * l2 + l3 * l3;
    float det = s11 * s22 - s12 * s12;
    float inv = 1.0f / det;
    float c0 =  s22 * inv;
    float c1 = -s12 * inv;
    float c2 =  s11 * inv;

    float cx = 0.5f * (mx + 1.0f) * (float)IMG_W;
    float cy = 0.5f * (my + 1.0f) * (float)IMG_H;

    float op = 1.0f / (1.0f + expf(-opacity[g]));
    float cr = 1.0f / (1.0f + expf(-fdc[3 * g]));
    float cg = 1.0f / (1.0f + expf(-fdc[3 * g + 1]));
    float cb = 1.0f / (1.0f + expf(-fdc[3 * g + 2]));

    // alpha = op*exp(-sigma) >= 1/255  =>  sigma <= log(255*op)
    float s_max = logf(255.0f * op);
    if (s_max < 0.0f) return;  // gaussian can never reach 1/255

    // conservative bbox from covariance diagonal (+1 px safety margin);
    // over-covered pixels are rejected by the exact per-pixel threshold below
    float rx = sqrtf(2.0f * s_max * s11) + 1.0f;
    float ry = sqrtf(2.0f * s_max * s22) + 1.0f;

    int w0 = max(0,         (int)floorf(cx - rx - 0.5f));
    int w1 = min(IMG_W - 1, (int)ceilf (cx + rx - 0.5f));
    int h0 = max(0,         (int)floorf(cy - ry - 0.5f));
    int h1 = min(IMG_H - 1, (int)ceilf (cy + ry - 0.5f));
    if (w1 < w0 || h1 < h0) return;

    int bw  = w1 - w0 + 1;
    int bh  = h1 - h0 + 1;
    int tot = bw * bh;

    for (int idx = lane; idx < tot; idx += 64) {
        int h = h0 + idx / bw;
        int w = w0 + idx % bw;
        float dx = cx - ((float)w + 0.5f);
        float dy = cy - ((float)h + 0.5f);
        // same association order as reference: (0.5c0dx^2 + 0.5c2dy^2) + c1*dy*dx
        float sigma = 0.5f * c0 * dx * dx + 0.5f * c2 * dy * dy + c1 * dy * dx;
        if (sigma < 0.0f) continue;
        float alpha = fminf(op * expf(-sigma), 0.999f);
        if (alpha < (1.0f / 255.0f)) continue;
        int p = h * IMG_W + w;
        atomicAdd(&out[0 * IMG_H * IMG_W + p], alpha * cr);
        atomicAdd(&out[1 * IMG_H * IMG_W + p], alpha * cg);
        atomicAdd(&out[2 * IMG_H * IMG_W + p], alpha * cb);
    }
}

__global__ void clip_kernel(float4* __restrict__ out, int n4) {
    int i = blockIdx.x * blockDim.x + threadIdx.x;
    if (i < n4) {
        float4 v = out[i];
        v.x = fminf(fmaxf(v.x, 0.0f), 1.0f);
        v.y = fminf(fmaxf(v.y, 0.0f), 1.0f);
        v.z = fminf(fmaxf(v.z, 0.0f), 1.0f);
        v.w = fminf(fmaxf(v.w, 0.0f), 1.0f);
        out[i] = v;
    }
}

extern "C" void kernel_launch(void* const* d_in, const int* in_sizes, int n_in,
                              void* d_out, int out_size, void* d_ws, size_t ws_size,
                              hipStream_t stream) {
    const float* xyz     = (const float*)d_in[0];  // (1, N, 2)
    const float* chol    = (const float*)d_in[1];  // (1, N, 3)
    const float* opacity = (const float*)d_in[2];  // (N, 1)
    const float* fdc     = (const float*)d_in[3];  // (N, 3)
    // d_in[4] = frame_index, always 0 (T == 1)

    float* out = (float*)d_out;                    // (1, 3, H, W) = 786432 floats
    int n4 = out_size / 4;                         // 196608 float4s

    zero_kernel<<<(n4 + 255) / 256, 256, 0, stream>>>((float4*)out, n4);
    splat_kernel<<<N_GAUSS, 64, 0, stream>>>(xyz, chol, opacity, fdc, out);
    clip_kernel<<<(n4 + 255) / 256, 256, 0, stream>>>((float4*)out, n4);
}